// Round 4
// baseline (704.798 us; speedup 1.0000x reference)
//
#include <hip/hip_runtime.h>
#include <hip/hip_bf16.h>
#include <cstdint>
#include <cstddef>

#define N_ACT 200000
#define CH 128
#define NOFF 27
#define TM 128

typedef __bf16 v8bf __attribute__((ext_vector_type(8)));
typedef float v4f __attribute__((ext_vector_type(4)));

__device__ __forceinline__ unsigned short f2bf(float f) {
    union { float f; unsigned int u; } x; x.f = f;
    unsigned int lsb = (x.u >> 16) & 1u;
    x.u += 0x7fffu + lsb;            // round-to-nearest-even
    return (unsigned short)(x.u >> 16);
}

// K1a: cast features fp32 -> bf16, 8 elements/thread
__global__ void cast_feat(const float* __restrict__ in,
                          unsigned short* __restrict__ out) {
    long long i = (long long)blockIdx.x * blockDim.x + threadIdx.x;
    long long base = i * 8;
    if (base >= (long long)N_ACT * CH) return;
    const float4* p = (const float4*)(in + base);
    float4 a = p[0], b = p[1];
    unsigned int w0 = (unsigned)f2bf(a.x) | ((unsigned)f2bf(a.y) << 16);
    unsigned int w1 = (unsigned)f2bf(a.z) | ((unsigned)f2bf(a.w) << 16);
    unsigned int w2 = (unsigned)f2bf(b.x) | ((unsigned)f2bf(b.y) << 16);
    unsigned int w3 = (unsigned)f2bf(b.z) | ((unsigned)f2bf(b.w) << 16);
    *(uint4*)(out + base) = make_uint4(w0, w1, w2, w3);
}

// K1b: pack W[k][cin][cout] fp32 into fragment-order bf16:
//   Wtp[(k*4+q)*4096 + (jkk*64 + lane)*8 + e]
// q = col-quarter (wave id), jkk = j*4+kk, lane = quad*16+lr,
// value = W[k][kk*32+quad*8+e][q*32+j*16+lr].
// -> each wave's 8 b-frag loads per k are 64 lanes x consecutive 16B (1 KB).
__global__ void prep_w(const float* __restrict__ W,
                       unsigned short* __restrict__ Wtp,
                       float* __restrict__ stats,
                       float* __restrict__ zpage) {
    int k = blockIdx.x;
    int t = threadIdx.x;
    if (k == 0 && t < 2 * CH) stats[t] = 0.0f;   // sums + sumsq
    if (k == 0 && t < 64) zpage[t] = 0.0f;       // 256 B zero row for gathers
    const float* wk = W + (size_t)k * CH * CH;
    for (int g = t; g < 2048; g += 256) {
        int q = g >> 9, r = g & 511;
        int jkk = r >> 6, lane = r & 63;
        int j = jkk >> 2, kk = jkk & 3;
        int lr = lane & 15, quad = lane >> 4;
        int cout = q * 32 + j * 16 + lr;
        int cin0 = kk * 32 + quad * 8;
        unsigned int wbuf[4];
        #pragma unroll
        for (int h = 0; h < 4; ++h) {
            unsigned short lo = f2bf(wk[(size_t)(cin0 + 2*h)     * CH + cout]);
            unsigned short hi = f2bf(wk[(size_t)(cin0 + 2*h + 1) * CH + cout]);
            wbuf[h] = (unsigned)lo | ((unsigned)hi << 16);
        }
        *(uint4*)(Wtp + ((size_t)(k * 4 + q) << 12) + (size_t)(jkk * 64 + lane) * 8)
            = make_uint4(wbuf[0], wbuf[1], wbuf[2], wbuf[3]);
    }
}

// K2: double-buffered LDS, 1-barrier/k async pipeline (T14 issue-early /
// write-late). Per k: issue gather loads for k+1 (global->reg, only needs
// idxL) | MFMA phase on buffer cur (covers the ~500-900cy gather latency) |
// vmcnt-drain + ds_write G -> buffer cur^1 | loadB(k+1) | barrier.
// Wave split: wid = cout-quarter, each wave computes 128 rows x 32 couts
// (the verified 405.8us decomposition; the 2x2 split regressed -> LDS read
// BW is not the limiter, gather-drain latency is).
__global__ __launch_bounds__(256, 2) void conv_mfma(
        const unsigned short* __restrict__ feat,   // [N][128] bf16
        const int* __restrict__ nbr,               // [27][N]
        const unsigned short* __restrict__ Wtp,    // packed (see prep_w)
        const unsigned short* __restrict__ zpage,  // 256 B of zeros
        float* __restrict__ out,                   // [N][128] conv result
        float* __restrict__ stats) {               // sums[128], sumsq[128]
    __shared__ __bf16 As[2 * TM * CH];             // 2 x 32 KB double buffer
    __shared__ int idxL[NOFF * TM];                // 13.8 KB
    __shared__ float sred[256];                    // 1 KB

    const int t    = threadIdx.x;
    const int row0 = blockIdx.x * TM;
    const int wid  = t >> 6;
    const int lane = t & 63;
    const int lr   = lane & 15;
    const int quad = lane >> 4;

    // ---- stage the whole neighbor-index table once (coalesced)
    for (int e = t; e < NOFF * TM; e += 256) {
        int k = e >> 7, r = e & 127;
        int gr = row0 + r;
        idxL[e] = (gr < N_ACT) ? nbr[(size_t)k * N_ACT + gr] : -1;
    }
    __syncthreads();

    v4f acc[8][2];
    #pragma unroll
    for (int i = 0; i < 8; ++i) {
        acc[i][0] = (v4f){0.f, 0.f, 0.f, 0.f};
        acc[i][1] = (v4f){0.f, 0.f, 0.f, 0.f};
    }

    // staging coords: thread t gathers chunk sc (16B) of rows p*16+sr0
    const int sc  = t & 15;
    const int sr0 = t >> 4;
    const unsigned short* zsrc = zpage + sc * 8;

    v8bf B[8];     // B fragments for current k
    uint4 G[8];    // in-flight gather for k+1 (held across the MFMA phase)

    // issue the 8 gather loads (global -> G regs); latency hides under MFMA
    auto issueG = [&](int k) {
        #pragma unroll
        for (int p = 0; p < 8; ++p) {
            int row = p * 16 + sr0;
            int idx = idxL[k * TM + row];
            const unsigned short* src =
                (idx >= 0) ? feat + ((size_t)idx << 7) + sc * 8 : zsrc;
            G[p] = *(const uint4*)src;
        }
    };
    // drain + write G into buffer b (rotated-chunk layout)
    auto writeAs = [&](int b) {
        __bf16* dst = As + b * (TM * CH);
        #pragma unroll
        for (int p = 0; p < 8; ++p) {
            int row = p * 16 + sr0;
            *(uint4*)(dst + row * CH + (((sc + row) & 15) << 3)) = G[p];
        }
    };
    auto loadB = [&](int k) {
        const unsigned short* base =
            Wtp + ((size_t)(k * 4 + wid) << 12) + (size_t)lane * 8;
        #pragma unroll
        for (int jkk = 0; jkk < 8; ++jkk)
            B[jkk] = *(const v8bf*)(base + jkk * 512);
    };
    // i-blocked: per row-subtile load 4 a-frags (16 regs), fire 8 MFMAs
    auto mfmaPhase = [&](const __bf16* buf) {
        #pragma unroll
        for (int i = 0; i < 8; ++i) {
            const __bf16* rowp = buf + (i * 16 + lr) * CH;
            v8bf a[4];
            #pragma unroll
            for (int kk = 0; kk < 4; ++kk)
                a[kk] = *(const v8bf*)(rowp + (((kk * 4 + quad + lr) & 15) << 3));
            #pragma unroll
            for (int kk = 0; kk < 4; ++kk) {
                acc[i][0] = __builtin_amdgcn_mfma_f32_16x16x32_bf16(
                    a[kk], B[kk], acc[i][0], 0, 0, 0);
                acc[i][1] = __builtin_amdgcn_mfma_f32_16x16x32_bf16(
                    a[kk], B[4 + kk], acc[i][1], 0, 0, 0);
            }
        }
    };

    // ---- prologue: stage k=0 into buffer 0
    issueG(0);
    writeAs(0);
    loadB(0);
    __syncthreads();

    // ---- k-loop: ONE barrier per k; gathers for k+1 in flight during MFMA.
    // Double buffer makes the pre-stage barrier unnecessary: iter k writes
    // buf^1 while (possibly slow) peers still read buf; the single barrier
    // orders "buf^1 complete" before iter k+1 reads it, and no wave can
    // rewrite buf until all passed that barrier (i.e. finished reading).
    int cur = 0;
    #pragma unroll 1
    for (int k = 0; k < NOFF; ++k) {
        const __bf16* buf = As + cur * (TM * CH);
        if (k + 1 < NOFF) issueG(k + 1);   // VMEM in flight across MFMA
        mfmaPhase(buf);
        if (k + 1 < NOFF) {
            writeAs(cur ^ 1);              // vmcnt drain happens here
            loadB(k + 1);                  // L2-resident B for next k
            __syncthreads();
            cur ^= 1;
        }
    }

    // ---- epilogue: store conv result + per-column partial stats
    float psum[2] = {0.f, 0.f};
    float psq[2]  = {0.f, 0.f};
    #pragma unroll
    for (int i = 0; i < 8; ++i) {
        #pragma unroll
        for (int r = 0; r < 4; ++r) {
            int grow = row0 + i * 16 + quad * 4 + r;
            if (grow < N_ACT) {
                #pragma unroll
                for (int j = 0; j < 2; ++j) {
                    float v = acc[i][j][r];
                    out[(size_t)grow * CH + wid * 32 + j * 16 + lr] = v;
                    psum[j] += v;
                    psq[j]  += v * v;
                }
            }
        }
    }
    #pragma unroll
    for (int j = 0; j < 2; ++j) {
        psum[j] += __shfl_xor(psum[j], 16, 64);
        psq[j]  += __shfl_xor(psq[j], 16, 64);
        psum[j] += __shfl_xor(psum[j], 32, 64);
        psq[j]  += __shfl_xor(psq[j], 32, 64);
    }
    if (quad == 0) {
        #pragma unroll
        for (int j = 0; j < 2; ++j) {
            int c = wid * 32 + j * 16 + lr;
            sred[c]       = psum[j];
            sred[128 + c] = psq[j];
        }
    }
    __syncthreads();
    if (t < CH) {
        atomicAdd(&stats[t],      sred[t]);
        atomicAdd(&stats[CH + t], sred[128 + t]);
    }
}

// K3: per-channel scale/shift from batch stats
__global__ void finalize_stats(const float* __restrict__ gamma,
                               const float* __restrict__ beta,
                               float* __restrict__ stats) {
    int c = threadIdx.x;
    if (c < CH) {
        float inv_n = 1.0f / (float)N_ACT;
        float mean  = stats[c] * inv_n;
        float var   = stats[CH + c] * inv_n - mean * mean;
        float sc    = gamma[c] * rsqrtf(var + 1e-4f);
        stats[2 * CH + c] = sc;
        stats[3 * CH + c] = beta[c] - mean * sc;
    }
}

// K4: out = relu(conv * scale[c] + shift[c]), float4
__global__ void bn_relu(const float* __restrict__ conv,
                        const float* __restrict__ stats,
                        float* __restrict__ out) {
    long long i = (long long)blockIdx.x * blockDim.x + threadIdx.x;
    if (i >= (long long)N_ACT * CH / 4) return;
    int c4 = (int)(i & 31) * 4;
    float4 v  = ((const float4*)conv)[i];
    float4 sc = *(const float4*)(stats + 2 * CH + c4);
    float4 sh = *(const float4*)(stats + 3 * CH + c4);
    float4 o;
    o.x = fmaxf(v.x * sc.x + sh.x, 0.f);
    o.y = fmaxf(v.y * sc.y + sh.y, 0.f);
    o.z = fmaxf(v.z * sc.z + sh.z, 0.f);
    o.w = fmaxf(v.w * sc.w + sh.w, 0.f);
    ((float4*)out)[i] = o;
}

extern "C" void kernel_launch(void* const* d_in, const int* in_sizes, int n_in,
                              void* d_out, int out_size, void* d_ws, size_t ws_size,
                              hipStream_t stream) {
    const float* features = (const float*)d_in[0];
    const int*   nbr      = (const int*)d_in[1];
    const float* W        = (const float*)d_in[2];
    const float* gamma    = (const float*)d_in[3];
    const float* beta     = (const float*)d_in[4];
    float* outp = (float*)d_out;

    char* ws = (char*)d_ws;
    // layout: feat_bf16 (51,200,000 B) | Wtp (884,736 B) | conv fp32
    // (102,400,000 B) | stats (512 floats) | zero page (256 B)
    unsigned short* feat_bf = (unsigned short*)ws;
    unsigned short* Wtp     = (unsigned short*)(ws + 51200000);
    float* conv             = (float*)(ws + 51200000 + 884736);
    float* stats            = (float*)(ws + 51200000 + 884736 + 102400000);
    float* zpage            = stats + 4 * CH;

    cast_feat<<<12500, 256, 0, stream>>>(features, feat_bf);
    prep_w<<<NOFF, 256, 0, stream>>>(W, Wtp, stats, zpage);
    conv_mfma<<<(N_ACT + TM - 1) / TM, 256, 0, stream>>>(
        feat_bf, nbr, Wtp, (const unsigned short*)zpage, conv, stats);
    finalize_stats<<<1, CH, 0, stream>>>(gamma, beta, stats);
    bn_relu<<<25000, 256, 0, stream>>>(conv, stats, outp);
}

// Round 5
// 399.269 us; speedup vs baseline: 1.7652x; 1.7652x over previous
//
#include <hip/hip_runtime.h>
#include <hip/hip_bf16.h>
#include <cstdint>
#include <cstddef>

#define N_ACT 200000
#define CH 128
#define NOFF 27
#define TM 96          // 96-row tile: acc 48 AGPR + ~75 VGPR < 128 unified
                       // -> 4 waves/SIMD -> 4 blocks/CU (was 2 at TM=128)

typedef __bf16 v8bf __attribute__((ext_vector_type(8)));
typedef float v4f __attribute__((ext_vector_type(4)));

__device__ __forceinline__ unsigned short f2bf(float f) {
    union { float f; unsigned int u; } x; x.f = f;
    unsigned int lsb = (x.u >> 16) & 1u;
    x.u += 0x7fffu + lsb;            // round-to-nearest-even
    return (unsigned short)(x.u >> 16);
}

// K1a: cast features fp32 -> bf16, 8 elements/thread
__global__ void cast_feat(const float* __restrict__ in,
                          unsigned short* __restrict__ out) {
    long long i = (long long)blockIdx.x * blockDim.x + threadIdx.x;
    long long base = i * 8;
    if (base >= (long long)N_ACT * CH) return;
    const float4* p = (const float4*)(in + base);
    float4 a = p[0], b = p[1];
    unsigned int w0 = (unsigned)f2bf(a.x) | ((unsigned)f2bf(a.y) << 16);
    unsigned int w1 = (unsigned)f2bf(a.z) | ((unsigned)f2bf(a.w) << 16);
    unsigned int w2 = (unsigned)f2bf(b.x) | ((unsigned)f2bf(b.y) << 16);
    unsigned int w3 = (unsigned)f2bf(b.z) | ((unsigned)f2bf(b.w) << 16);
    *(uint4*)(out + base) = make_uint4(w0, w1, w2, w3);
}

// K1b: pack W[k][cin][cout] fp32 into fragment-order bf16:
//   Wtp[(k*4+q)*4096 + (jkk*64 + lane)*8 + e]
// q = col-quarter (wave id), jkk = j*4+kk, lane = quad*16+lr,
// value = W[k][kk*32+quad*8+e][q*32+j*16+lr].
// -> each wave's 8 b-frag loads per k are 64 lanes x consecutive 16B (1 KB).
__global__ void prep_w(const float* __restrict__ W,
                       unsigned short* __restrict__ Wtp,
                       float* __restrict__ stats,
                       float* __restrict__ zpage) {
    int k = blockIdx.x;
    int t = threadIdx.x;
    if (k == 0 && t < 2 * CH) stats[t] = 0.0f;   // sums + sumsq
    if (k == 0 && t < 64) zpage[t] = 0.0f;       // 256 B zero row for gathers
    const float* wk = W + (size_t)k * CH * CH;
    for (int g = t; g < 2048; g += 256) {
        int q = g >> 9, r = g & 511;
        int jkk = r >> 6, lane = r & 63;
        int j = jkk >> 2, kk = jkk & 3;
        int lr = lane & 15, quad = lane >> 4;
        int cout = q * 32 + j * 16 + lr;
        int cin0 = kk * 32 + quad * 8;
        unsigned int wbuf[4];
        #pragma unroll
        for (int h = 0; h < 4; ++h) {
            unsigned short lo = f2bf(wk[(size_t)(cin0 + 2*h)     * CH + cout]);
            unsigned short hi = f2bf(wk[(size_t)(cin0 + 2*h + 1) * CH + cout]);
            wbuf[h] = (unsigned)lo | ((unsigned)hi << 16);
        }
        *(uint4*)(Wtp + ((size_t)(k * 4 + q) << 12) + (size_t)(jkk * 64 + lane) * 8)
            = make_uint4(wbuf[0], wbuf[1], wbuf[2], wbuf[3]);
    }
}

// K2: verified 2-barrier single-buffer structure (405.8us baseline), with
// TM=96 to cut the unified-register footprint (acc 64->48 AGPR) below the
// 128-reg band: 4 waves/SIMD -> 4 blocks/CU co-resident (was 2). One
// block's barrier-drained gather phase now overlaps THREE other blocks'
// MFMA phases instead of one. LDS 35.2 KB -> 4 blocks fit.
__global__ __launch_bounds__(256, 4) void conv_mfma(
        const unsigned short* __restrict__ feat,   // [N][128] bf16
        const int* __restrict__ nbr,               // [27][N]
        const unsigned short* __restrict__ Wtp,    // packed (see prep_w)
        const unsigned short* __restrict__ zpage,  // 256 B of zeros
        float* __restrict__ out,                   // [N][128] conv result
        float* __restrict__ stats) {               // sums[128], sumsq[128]
    __shared__ __bf16 As[TM * CH];                 // 24 KB, rotated chunks
    __shared__ int idxL[NOFF * TM];                // 10.1 KB
    __shared__ float sred[256];                    // 1 KB

    const int t    = threadIdx.x;
    const int row0 = blockIdx.x * TM;
    const int wid  = t >> 6;
    const int lane = t & 63;
    const int lr   = lane & 15;
    const int quad = lane >> 4;

    // ---- stage the whole neighbor-index table once (coalesced)
    for (int e = t; e < NOFF * TM; e += 256) {
        int k = e / TM, r = e - k * TM;
        int gr = row0 + r;
        idxL[e] = (gr < N_ACT) ? nbr[(size_t)k * N_ACT + gr] : -1;
    }
    __syncthreads();

    v4f acc[6][2];
    #pragma unroll
    for (int i = 0; i < 6; ++i) {
        acc[i][0] = (v4f){0.f, 0.f, 0.f, 0.f};
        acc[i][1] = (v4f){0.f, 0.f, 0.f, 0.f};
    }

    // staging coords: thread t gathers chunk sc (16B) of rows p*16+sr0
    const int sc  = t & 15;
    const int sr0 = t >> 4;
    const unsigned short* zsrc = zpage + sc * 8;

    v8bf B[8];           // single B fragment set (lives across MFMA phase)

    // gather + immediate LDS write: G regs live only inside this function
    auto stageA = [&](int k) {
        uint4 G[6];
        #pragma unroll
        for (int p = 0; p < 6; ++p) {
            int row = p * 16 + sr0;
            int idx = idxL[k * TM + row];
            const unsigned short* src =
                (idx >= 0) ? feat + ((size_t)idx << 7) + sc * 8 : zsrc;
            G[p] = *(const uint4*)src;
        }
        #pragma unroll
        for (int p = 0; p < 6; ++p) {
            int row = p * 16 + sr0;
            *(uint4*)(As + row * CH + (((sc + row) & 15) << 3)) = G[p];
        }
    };
    auto loadB = [&](int k) {
        const unsigned short* base =
            Wtp + ((size_t)(k * 4 + wid) << 12) + (size_t)lane * 8;
        #pragma unroll
        for (int jkk = 0; jkk < 8; ++jkk)
            B[jkk] = *(const v8bf*)(base + jkk * 512);
    };
    // i-blocked: per row-subtile load 4 a-frags (16 regs), fire 8 MFMAs
    auto mfmaPhase = [&]() {
        #pragma unroll
        for (int i = 0; i < 6; ++i) {
            const __bf16* rowp = As + (i * 16 + lr) * CH;
            v8bf a[4];
            #pragma unroll
            for (int kk = 0; kk < 4; ++kk)
                a[kk] = *(const v8bf*)(rowp + (((kk * 4 + quad + lr) & 15) << 3));
            #pragma unroll
            for (int kk = 0; kk < 4; ++kk) {
                acc[i][0] = __builtin_amdgcn_mfma_f32_16x16x32_bf16(
                    a[kk], B[kk], acc[i][0], 0, 0, 0);
                acc[i][1] = __builtin_amdgcn_mfma_f32_16x16x32_bf16(
                    a[kk], B[4 + kk], acc[i][1], 0, 0, 0);
            }
        }
    };

    // ---- prologue: stage k=0
    stageA(0);
    loadB(0);
    __syncthreads();

    // ---- k-loop: 2 barriers, single buffer, no G-hold across MFMA
    #pragma unroll 1
    for (int k = 0; k < NOFF; ++k) {
        mfmaPhase();
        if (k + 1 < NOFF) {
            __syncthreads();       // everyone done reading As / B consumed
            stageA(k + 1);         // gather -> immediate ds_write (G dies)
            loadB(k + 1);          // B latency hides behind gather drain
            __syncthreads();       // stage complete
        }
    }

    // ---- epilogue: store conv result + per-column partial stats
    float psum[2] = {0.f, 0.f};
    float psq[2]  = {0.f, 0.f};
    #pragma unroll
    for (int i = 0; i < 6; ++i) {
        #pragma unroll
        for (int r = 0; r < 4; ++r) {
            int grow = row0 + i * 16 + quad * 4 + r;
            if (grow < N_ACT) {
                #pragma unroll
                for (int j = 0; j < 2; ++j) {
                    float v = acc[i][j][r];
                    out[(size_t)grow * CH + wid * 32 + j * 16 + lr] = v;
                    psum[j] += v;
                    psq[j]  += v * v;
                }
            }
        }
    }
    #pragma unroll
    for (int j = 0; j < 2; ++j) {
        psum[j] += __shfl_xor(psum[j], 16, 64);
        psq[j]  += __shfl_xor(psq[j], 16, 64);
        psum[j] += __shfl_xor(psum[j], 32, 64);
        psq[j]  += __shfl_xor(psq[j], 32, 64);
    }
    if (quad == 0) {
        #pragma unroll
        for (int j = 0; j < 2; ++j) {
            int c = wid * 32 + j * 16 + lr;
            sred[c]       = psum[j];
            sred[128 + c] = psq[j];
        }
    }
    __syncthreads();
    if (t < CH) {
        atomicAdd(&stats[t],      sred[t]);
        atomicAdd(&stats[CH + t], sred[128 + t]);
    }
}

// K3: per-channel scale/shift from batch stats
__global__ void finalize_stats(const float* __restrict__ gamma,
                               const float* __restrict__ beta,
                               float* __restrict__ stats) {
    int c = threadIdx.x;
    if (c < CH) {
        float inv_n = 1.0f / (float)N_ACT;
        float mean  = stats[c] * inv_n;
        float var   = stats[CH + c] * inv_n - mean * mean;
        float sc    = gamma[c] * rsqrtf(var + 1e-4f);
        stats[2 * CH + c] = sc;
        stats[3 * CH + c] = beta[c] - mean * sc;
    }
}

// K4: out = relu(conv * scale[c] + shift[c]), float4
__global__ void bn_relu(const float* __restrict__ conv,
                        const float* __restrict__ stats,
                        float* __restrict__ out) {
    long long i = (long long)blockIdx.x * blockDim.x + threadIdx.x;
    if (i >= (long long)N_ACT * CH / 4) return;
    int c4 = (int)(i & 31) * 4;
    float4 v  = ((const float4*)conv)[i];
    float4 sc = *(const float4*)(stats + 2 * CH + c4);
    float4 sh = *(const float4*)(stats + 3 * CH + c4);
    float4 o;
    o.x = fmaxf(v.x * sc.x + sh.x, 0.f);
    o.y = fmaxf(v.y * sc.y + sh.y, 0.f);
    o.z = fmaxf(v.z * sc.z + sh.z, 0.f);
    o.w = fmaxf(v.w * sc.w + sh.w, 0.f);
    ((float4*)out)[i] = o;
}

extern "C" void kernel_launch(void* const* d_in, const int* in_sizes, int n_in,
                              void* d_out, int out_size, void* d_ws, size_t ws_size,
                              hipStream_t stream) {
    const float* features = (const float*)d_in[0];
    const int*   nbr      = (const int*)d_in[1];
    const float* W        = (const float*)d_in[2];
    const float* gamma    = (const float*)d_in[3];
    const float* beta     = (const float*)d_in[4];
    float* outp = (float*)d_out;

    char* ws = (char*)d_ws;
    // layout: feat_bf16 (51,200,000 B) | Wtp (884,736 B) | conv fp32
    // (102,400,000 B) | stats (512 floats) | zero page (256 B)
    unsigned short* feat_bf = (unsigned short*)ws;
    unsigned short* Wtp     = (unsigned short*)(ws + 51200000);
    float* conv             = (float*)(ws + 51200000 + 884736);
    float* stats            = (float*)(ws + 51200000 + 884736 + 102400000);
    float* zpage            = stats + 4 * CH;

    cast_feat<<<12500, 256, 0, stream>>>(features, feat_bf);
    prep_w<<<NOFF, 256, 0, stream>>>(W, Wtp, stats, zpage);
    conv_mfma<<<(N_ACT + TM - 1) / TM, 256, 0, stream>>>(
        feat_bf, nbr, Wtp, (const unsigned short*)zpage, conv, stats);
    finalize_stats<<<1, CH, 0, stream>>>(gamma, beta, stats);
    bn_relu<<<25000, 256, 0, stream>>>(conv, stats, outp);
}